// Round 10
// baseline (39.375 us; speedup 1.0000x reference)
//
#include <hip/hip_runtime.h>

#define Bn 128
#define Qn 32
#define Dn 512
#define En 300
#define Kn 21
#define NC 16                  // 32-doc chunks per batch
#define CH 32
#define NKT 10                 // k-tiles of 32 floats (320 >= 300, zero-padded)
#define ROWB 640               // bytes per packed bf16 row (320 bf16)
#define SIMLD 36               // sim row stride (floats)
#define NTHR 256
#define QK (Qn * Kn)

typedef __attribute__((ext_vector_type(8))) short bf16x8;
typedef __attribute__((ext_vector_type(4))) float f32x4;

// LDS map (bytes):
//   dbuf [0, 20480)        bf16[32][320], XOR-swizzled rows
//   sim  [20480, 25088)    float[32][SIMLD]
//   invd [25088, 25216)    float[32]
//   invq [25216, 25344)    float[32]
#define SIM_OFF  20480
#define INVD_OFF 25088
#define INVQ_OFF 25216
#define SMEM_BYTES 25344       // LDS allows 6 blocks/CU; VGPR caps at 3

#define SWZ(r, byte) ((byte) ^ (((r) & 7) << 4))   // T2 swizzle, same on write+read

__device__ __forceinline__ float dot4(float4 a, float4 b) {
    return a.x * b.x + a.y * b.y + a.z * b.z + a.w * b.w;
}

// 8 raw floats -> bf16x8 (round-half-up; validated R4-R9, absmax <= 0.016)
__device__ __forceinline__ bf16x8 pack8r(float4 lo, float4 hi) {
    uint4 u;
    u.x = __builtin_amdgcn_perm(__float_as_uint(lo.y) + 0x8000u,
                                __float_as_uint(lo.x) + 0x8000u, 0x07060302u);
    u.y = __builtin_amdgcn_perm(__float_as_uint(lo.w) + 0x8000u,
                                __float_as_uint(lo.z) + 0x8000u, 0x07060302u);
    u.z = __builtin_amdgcn_perm(__float_as_uint(hi.y) + 0x8000u,
                                __float_as_uint(hi.x) + 0x8000u, 0x07060302u);
    u.w = __builtin_amdgcn_perm(__float_as_uint(hi.w) + 0x8000u,
                                __float_as_uint(hi.z) + 0x8000u, 0x07060302u);
    union { uint4 u4; bf16x8 v; } cv; cv.u4 = u;
    return cv.v;
}

__global__ __launch_bounds__(NTHR, 3)
void knrm_main(const int* __restrict__ qidx, const int* __restrict__ didx,
               const int* __restrict__ dlen_arr, const float* __restrict__ table,
               float* __restrict__ partial)
{
    // XCD-contiguous remap (2048 % 8 == 0, bijective): a batch's 16 blocks share an XCD
    const int g = blockIdx.x;
    const int idx2 = (g & 7) * 256 + (g >> 3);
    const int b = idx2 >> 4;
    const int c = idx2 & 15;
    const int dlen = dlen_arr[b];
    if (c * CH >= dlen) return;      // inactive: reduce kernel never reads this slice

    const int t = threadIdx.x;
    const int lane = t & 63;
    const int w = t >> 6;            // wave -> (qt, dt) quadrant
    const int qt = w >> 1;
    const int dt = w & 1;
    const int frow = lane & 15;
    const int koct = lane >> 4;
    const int row = t >> 3;          // d-staging: one row per 8-lane octet
    const int il  = t & 7;

    __shared__ __align__(16) char smem[SMEM_BYTES];
    char*  dbuf = smem;
    float* sim  = (float*)(smem + SIM_OFF);
    float* invd = (float*)(smem + INVD_OFF);
    float* invq = (float*)(smem + INVQ_OFF);

    // ---- tokens: direct per-thread loads (no LDS stage, no extra barrier)
    const int qrow_i = qt * 16 + frow;
    const int qtok = qidx[b * Qn + qrow_i];
    const int dstage = c * CH + row;
    const int dtok = (dstage < dlen) ? didx[b * Dn + dstage] : -1;
    const float* qrow = table + (size_t)qtok * En;
    const float* drow = table + (size_t)dtok * En;
    const float4 z4 = make_float4(0.f, 0.f, 0.f, 0.f);

    // ---- issue ALL gathers up front (one latency window)
    // d: lane covers 16B slots {il + 8i} of its octet's packed row
    float4 ldd[10];
    #pragma unroll
    for (int i = 0; i < 5; ++i) {
        const int f0 = (il + 8 * i) * 8;
        ldd[2*i]   = (f0     <= 296 && dtok >= 0) ? *(const float4*)(drow + f0)     : z4;
        ldd[2*i+1] = (f0 + 4 <= 296 && dtok >= 0) ? *(const float4*)(drow + f0 + 4) : z4;
    }
    // q: lane loads its own MFMA A-fragment slices (row qrow_i, k = kt*32+koct*8)
    float4 lq[20];
    #pragma unroll
    for (int kt = 0; kt < NKT; ++kt) {
        const int f0 = kt * 32 + koct * 8;
        lq[2*kt]   = (f0     <= 296) ? *(const float4*)(qrow + f0)     : z4;
        lq[2*kt+1] = (f0 + 4 <= 296) ? *(const float4*)(qrow + f0 + 4) : z4;
    }

    // ---- d: raw pack + swizzled b128 commit, then octet norm
    float ssd = 0.f;
    #pragma unroll
    for (int i = 0; i < 10; ++i) ssd += dot4(ldd[i], ldd[i]);
    #pragma unroll
    for (int i = 0; i < 5; ++i) {
        const int slot = il + 8 * i;
        const bf16x8 p = pack8r(ldd[2*i], ldd[2*i+1]);
        *(bf16x8*)(dbuf + SWZ(row, row * ROWB + slot * 16)) = p;
    }
    ssd += __shfl_xor(ssd, 1);
    ssd += __shfl_xor(ssd, 2);
    ssd += __shfl_xor(ssd, 4);
    if (il == 0) invd[row] = 1.0f / fmaxf(sqrtf(ssd), 1e-12f);

    // ---- q: raw pack to registers + cross-koct norm
    float ssq = 0.f;
    bf16x8 af[NKT];
    #pragma unroll
    for (int kt = 0; kt < NKT; ++kt) {
        ssq += dot4(lq[2*kt], lq[2*kt]) + dot4(lq[2*kt+1], lq[2*kt+1]);
        af[kt] = pack8r(lq[2*kt], lq[2*kt+1]);
    }
    ssq += __shfl_xor(ssq, 16);
    ssq += __shfl_xor(ssq, 32);
    if (dt == 0 && koct == 0) invq[qrow_i] = 1.0f / fmaxf(sqrtf(ssq), 1e-12f);

    __syncthreads();             // dbuf + norms ready

    // ---- 10 MFMAs (B from swizzled LDS), scale + sim write
    const int dr = dt * 16 + frow;
    f32x4 accS = {0.f, 0.f, 0.f, 0.f};
    #pragma unroll
    for (int kt = 0; kt < NKT; ++kt) {
        const bf16x8 bf = *(const bf16x8*)(dbuf + SWZ(dr, dr * ROWB + kt * 64 + koct * 16));
        accS = __builtin_amdgcn_mfma_f32_16x16x32_bf16(af[kt], bf, accS, 0, 0, 0);
    }
    // C layout: col = frow (doc), row = koct*4 + r (q within tile)
    const float idd = invd[dr];
    #pragma unroll
    for (int r = 0; r < 4; ++r) {
        const int q = qt * 16 + koct * 4 + r;
        sim[q * SIMLD + dr] = accS[r] * invq[q] * idd;
    }
    __syncthreads();

    // ---- pooling: thread = (q row, k-triple); stream 32 docs from sim
    const int pq = t >> 3;
    const int kg = t & 7;
    if (kg < 7) {
        float mu[3], cf[3];
        #pragma unroll
        for (int kk = 0; kk < 3; ++kk) {
            const int k = kg * 3 + kk;
            mu[kk] = (k == 0) ? 1.0f : 1.05f - 0.1f * (float)k;
            cf[kk] = (k == 0) ? -500000.0f : -50.0f;   // -1/(2*sigma^2)
        }
        float acc[3] = {0.f, 0.f, 0.f};
        const int cbase = c * CH;
        #pragma unroll
        for (int f4 = 0; f4 < 8; ++f4) {
            const float4 sv = *(const float4*)&sim[pq * SIMLD + f4 * 4];
            #pragma unroll
            for (int e = 0; e < 4; ++e) {
                const float se = (e == 0) ? sv.x : (e == 1) ? sv.y : (e == 2) ? sv.z : sv.w;
                const float s = (cbase + f4 * 4 + e < dlen) ? se : 1.0e3f;  // masked -> exp 0
                #pragma unroll
                for (int kk = 0; kk < 3; ++kk) {
                    const float d = s - mu[kk];
                    acc[kk] += __expf(cf[kk] * d * d);
                }
            }
        }
        float* pb = partial + (size_t)(b * NC + c) * QK + pq * Kn + kg * 3;
        pb[0] = acc[0]; pb[1] = acc[1]; pb[2] = acc[2];
    }
}

__global__ __launch_bounds__(704)
void knrm_reduce(const int* __restrict__ qlen_arr, const int* __restrict__ dlen_arr,
                 const float* __restrict__ partial, const float* __restrict__ dense_w,
                 const float* __restrict__ dense_b, float* __restrict__ out)
{
    __shared__ float sq[QK];
    __shared__ float lk[Kn];
    const int b = blockIdx.x;
    const int t = threadIdx.x;
    const int qlen = qlen_arr[b];
    const int ncu = min((dlen_arr[b] + CH - 1) >> 5, NC);   // only written slices
    if (t < QK) {
        const int q = t / Kn;
        float s = 0.f;
        for (int c = 0; c < ncu; ++c)
            s += partial[(size_t)(b * NC + c) * QK + t];
        sq[t] = (q < qlen) ? 0.01f * logf(fmaxf(s, 1e-10f)) : 0.f;
    }
    __syncthreads();
    if (t < Kn) {
        float l = 0.f;
        #pragma unroll
        for (int q = 0; q < Qn; ++q) l += sq[q * Kn + t];
        out[Bn + (size_t)b * Kn + t] = l;   // log_pooling_sum (B,K)
        lk[t] = l;
    }
    __syncthreads();
    if (t == 0) {
        float sc = dense_b[0];
        #pragma unroll
        for (int k = 0; k < Kn; ++k) sc += lk[k] * dense_w[k];
        out[b] = sc;                        // score (B,)
    }
}

extern "C" void kernel_launch(void* const* d_in, const int* in_sizes, int n_in,
                              void* d_out, int out_size, void* d_ws, size_t ws_size,
                              hipStream_t stream)
{
    const int*   qidx  = (const int*)d_in[0];
    const int*   didx  = (const int*)d_in[1];
    const int*   qlen  = (const int*)d_in[2];
    const int*   dlen  = (const int*)d_in[3];
    const float* table = (const float*)d_in[4];
    const float* dw    = (const float*)d_in[5];
    const float* db    = (const float*)d_in[6];
    float* out     = (float*)d_out;
    float* partial = (float*)d_ws;   // 5.5 MB; only slices with c < ceil(dlen/32) are read

    knrm_main<<<dim3(Bn * NC), dim3(NTHR), 0, stream>>>(qidx, didx, dlen, table, partial);
    knrm_reduce<<<dim3(Bn), dim3(704), 0, stream>>>(qlen, dlen, partial, dw, db, out);
}